// Round 1
// baseline (2329.471 us; speedup 1.0000x reference)
//
#include <hip/hip_runtime.h>
#include <math.h>

namespace {

constexpr int TSEQ  = 2048;
constexpr int DIN   = 16;
constexpr int NH1   = 5;
constexpr int NH2   = 50;
constexpr int NCLS  = 20;
constexpr int CHUNK = 64;
constexpr int BATCH = 256;

__device__ __forceinline__ float sigm(float x) {
    x = fminf(fmaxf(x, -30.f), 30.f);
    float e = __expf(-x);
    return __fdividef(1.f, 1.f + e);
}

__device__ __forceinline__ float tanh_fast(float x) {
    float ax = fabsf(x);
    float e  = __expf(-2.f * ax);
    float t  = __fdividef(1.f - e, 1.f + e);
    return copysignf(t, x);
}

// One block (one wave, 64 lanes) per batch element. Whole 2-layer LSTM
// recurrence + FC head fused; recurrent state lives in registers/LDS.
__global__ __launch_bounds__(64, 1) void lstm_fused_kernel(
    const float* __restrict__ x,     // (256,2048,16)
    const float* __restrict__ W1ih,  // (20,16)
    const float* __restrict__ W1hh,  // (20,5)
    const float* __restrict__ b1ih,  // (20)
    const float* __restrict__ b1hh,  // (20)
    const float* __restrict__ W2ih,  // (200,5)
    const float* __restrict__ W2hh,  // (200,50)
    const float* __restrict__ b2ih,  // (200)
    const float* __restrict__ b2hh,  // (200)
    const float* __restrict__ Wfc,   // (20,50)
    const float* __restrict__ bfc,   // (20)
    float* __restrict__ out)         // result(256,20) ++ last(256,50)
{
    const int b   = blockIdx.x;
    const int tid = threadIdx.x;

    __shared__ __align__(16) float s_x[CHUNK * DIN];  // 4 KB x-stage
    __shared__ float s_g1[NCLS];                      // layer-1 gate activations
    __shared__ float s_h1[8];                         // layer-1 hidden (pad)
    __shared__ __align__(16) float s_h2[52];          // layer-2 hidden (pad to 52)

    if (tid < 52) s_h2[tid] = 0.f;
    if (tid < 8)  s_h1[tid] = 0.f;

    // ---- layer-1 per-lane weights (lanes 0..19 own gate row tid) ----
    const int r1 = (tid < NCLS) ? tid : 0;
    float w1x[DIN], w1h[NH1], bias1;
    {
        const float4* w4 = (const float4*)(W1ih + r1 * DIN);  // 64B-aligned rows
        #pragma unroll
        for (int i = 0; i < 4; ++i) {
            float4 v = w4[i];
            w1x[4*i+0] = v.x; w1x[4*i+1] = v.y; w1x[4*i+2] = v.z; w1x[4*i+3] = v.w;
        }
        #pragma unroll
        for (int j = 0; j < NH1; ++j) w1h[j] = W1hh[r1 * NH1 + j];
        bias1 = b1ih[r1] + b1hh[r1];
    }

    // ---- layer-2 per-lane weights (lanes 0..49 own hidden unit tid;
    //      each lane holds its 4 gate rows i/f/g/o of W2hh in VGPRs) ----
    const int k = (tid < NH2) ? tid : 0;
    float w2hh[4][52];                      // padded to 52; [50],[51]=0
    #pragma unroll
    for (int gi = 0; gi < 4; ++gi) {
        const float2* r2 = (const float2*)(W2hh + (gi * NH2 + k) * NH2);  // 200B rows -> 8B aligned
        #pragma unroll
        for (int j = 0; j < 25; ++j) {
            float2 v = r2[j];
            w2hh[gi][2*j+0] = v.x;
            w2hh[gi][2*j+1] = v.y;
        }
        w2hh[gi][50] = 0.f;
        w2hh[gi][51] = 0.f;
    }
    float w2ih[4][NH1];
    #pragma unroll
    for (int gi = 0; gi < 4; ++gi)
        #pragma unroll
        for (int d = 0; d < NH1; ++d)
            w2ih[gi][d] = W2ih[(gi * NH2 + k) * NH1 + d];
    float bias2[4];
    #pragma unroll
    for (int gi = 0; gi < 4; ++gi)
        bias2[gi] = b2ih[gi * NH2 + k] + b2hh[gi * NH2 + k];

    float c1 = 0.f, c2 = 0.f, h2own = 0.f;
    const float* xb = x + (size_t)b * TSEQ * DIN;
    const bool is_g_row = (tid >= 10 && tid < 15);   // rows 10..14 = g gate (tanh)

    #pragma unroll 1
    for (int t0 = 0; t0 < TSEQ; t0 += CHUNK) {
        __syncthreads();   // previous chunk's s_x readers done
        {
            // stage 64 timesteps of x: 1024 floats, coalesced float4
            const float4* src = (const float4*)(xb + t0 * DIN);
            float4* dst = (float4*)s_x;
            #pragma unroll
            for (int i = 0; i < 4; ++i) dst[tid + 64*i] = src[tid + 64*i];
        }
        __syncthreads();

        #pragma unroll 1
        for (int tt = 0; tt < CHUNK; ++tt) {
            // ---------------- layer 1 (lanes 0..19, one gate row each) ----------------
            const float* xt = s_x + tt * DIN;
            float g = bias1;
            #pragma unroll
            for (int d = 0; d < DIN; ++d) g = fmaf(xt[d], w1x[d], g);   // LDS broadcast
            #pragma unroll
            for (int j = 0; j < NH1; ++j) g = fmaf(s_h1[j], w1h[j], g);
            float act_s = sigm(g);
            float act_t = tanh_fast(g);
            if (tid < NCLS) s_g1[tid] = is_g_row ? act_t : act_s;
            __syncthreads();
            if (tid < NH1) {
                float i_ = s_g1[tid];
                float f_ = s_g1[tid + 5];
                float g_ = s_g1[tid + 10];
                float o_ = s_g1[tid + 15];
                c1 = fmaf(f_, c1, i_ * g_);
                s_h1[tid] = o_ * tanh_fast(c1);
            }
            __syncthreads();

            // ---------------- layer 2 (lanes 0..49, one hidden unit each) -------------
            float a0 = bias2[0], a1 = bias2[1], a2 = bias2[2], a3 = bias2[3];
            #pragma unroll
            for (int d = 0; d < NH1; ++d) {
                float hv = s_h1[d];
                a0 = fmaf(hv, w2ih[0][d], a0);
                a1 = fmaf(hv, w2ih[1][d], a1);
                a2 = fmaf(hv, w2ih[2][d], a2);
                a3 = fmaf(hv, w2ih[3][d], a3);
            }
            const float4* h2v = (const float4*)s_h2;
            #pragma unroll
            for (int j4 = 0; j4 < 13; ++j4) {       // 13 x ds_read_b128 broadcast
                float4 hv = h2v[j4];
                const int j = 4 * j4;
                a0 = fmaf(hv.x, w2hh[0][j+0], a0);
                a1 = fmaf(hv.x, w2hh[1][j+0], a1);
                a2 = fmaf(hv.x, w2hh[2][j+0], a2);
                a3 = fmaf(hv.x, w2hh[3][j+0], a3);
                a0 = fmaf(hv.y, w2hh[0][j+1], a0);
                a1 = fmaf(hv.y, w2hh[1][j+1], a1);
                a2 = fmaf(hv.y, w2hh[2][j+1], a2);
                a3 = fmaf(hv.y, w2hh[3][j+1], a3);
                a0 = fmaf(hv.z, w2hh[0][j+2], a0);
                a1 = fmaf(hv.z, w2hh[1][j+2], a1);
                a2 = fmaf(hv.z, w2hh[2][j+2], a2);
                a3 = fmaf(hv.z, w2hh[3][j+2], a3);
                a0 = fmaf(hv.w, w2hh[0][j+3], a0);
                a1 = fmaf(hv.w, w2hh[1][j+3], a1);
                a2 = fmaf(hv.w, w2hh[2][j+3], a2);
                a3 = fmaf(hv.w, w2hh[3][j+3], a3);
            }
            float i2 = sigm(a0);
            float f2 = sigm(a1);
            float g2 = tanh_fast(a2);
            float o2 = sigm(a3);
            c2 = fmaf(f2, c2, i2 * g2);
            float hnew = o2 * tanh_fast(c2);
            __syncthreads();                 // all lanes done reading old s_h2
            if (tid < NH2) { s_h2[tid] = hnew; h2own = hnew; }
            __syncthreads();
        }
    }

    // ---- outputs: result(256,20) at offset 0, last(256,50) at offset 5120 ----
    if (tid < NH2) out[BATCH * NCLS + b * NH2 + tid] = h2own;
    if (tid < NCLS) {
        float acc = bfc[tid];
        const float* wr = Wfc + tid * NH2;
        #pragma unroll
        for (int j = 0; j < NH2; ++j) acc = fmaf(s_h2[j], wr[j], acc);
        out[b * NCLS + tid] = acc;
    }
}

} // namespace

extern "C" void kernel_launch(void* const* d_in, const int* in_sizes, int n_in,
                              void* d_out, int out_size, void* d_ws, size_t ws_size,
                              hipStream_t stream) {
    (void)in_sizes; (void)n_in; (void)d_ws; (void)ws_size; (void)out_size;
    const float* x    = (const float*)d_in[0];
    const float* W1ih = (const float*)d_in[1];
    const float* W1hh = (const float*)d_in[2];
    const float* b1ih = (const float*)d_in[3];
    const float* b1hh = (const float*)d_in[4];
    const float* W2ih = (const float*)d_in[5];
    const float* W2hh = (const float*)d_in[6];
    const float* b2ih = (const float*)d_in[7];
    const float* b2hh = (const float*)d_in[8];
    const float* Wfc  = (const float*)d_in[9];
    const float* bfc  = (const float*)d_in[10];

    lstm_fused_kernel<<<dim3(BATCH), dim3(64), 0, stream>>>(
        x, W1ih, W1hh, b1ih, b1hh, W2ih, W2hh, b2ih, b2hh, Wfc, bfc,
        (float*)d_out);
}

// Round 2
// 2017.517 us; speedup vs baseline: 1.1546x; 1.1546x over previous
//
#include <hip/hip_runtime.h>
#include <math.h>

namespace {

constexpr int TSEQ   = 2048;
constexpr int DIN    = 16;
constexpr int NH1    = 5;
constexpr int NH2    = 50;
constexpr int NCLS   = 20;
constexpr int CHUNK  = 64;
constexpr int NCHUNK = TSEQ / CHUNK;
constexpr int BATCH  = 256;
constexpr int GXS    = 21;   // gx LDS row stride (odd -> conflict-free)

__device__ __forceinline__ float fast_sigm(float x) {
    x = fminf(fmaxf(x, -30.f), 30.f);
    float e = __expf(-x);
    return __fdividef(1.f, 1.f + e);            // v_rcp + mul
}
// tanh(x) = 2*sigm(2x) - 1
__device__ __forceinline__ float fast_tanh(float x) {
    return fmaf(2.f, fast_sigm(2.f * x), -1.f);
}

__device__ __forceinline__ float2 fma2(float h, float2 w, float2 a) {
    a.x = fmaf(h, w.x, a.x);
    a.y = fmaf(h, w.y, a.y);
    return a;
}

// One block = one wave = one batch element. Fully wave-synchronous:
// no __syncthreads anywhere; cross-lane via __shfl and same-wave LDS
// (LDS ops from a single wave complete in order; wave_barrier pins
// compiler ordering).
__global__ __launch_bounds__(64, 1) void lstm_fused_kernel(
    const float* __restrict__ x,     // (256,2048,16)
    const float* __restrict__ W1ih,  // (20,16)
    const float* __restrict__ W1hh,  // (20,5)
    const float* __restrict__ b1ih,  // (20)
    const float* __restrict__ b1hh,  // (20)
    const float* __restrict__ W2ih,  // (200,5)
    const float* __restrict__ W2hh,  // (200,50)
    const float* __restrict__ b2ih,  // (200)
    const float* __restrict__ b2hh,  // (200)
    const float* __restrict__ Wfc,   // (20,50)
    const float* __restrict__ bfc,   // (20)
    float* __restrict__ out)         // result(256,20) ++ last(256,50)
{
    const int b   = blockIdx.x;
    const int tid = threadIdx.x;

    __shared__ __align__(16) float s_w1[NCLS * DIN];     // W1ih, row-major
    __shared__ __align__(16) float s_gx[CHUNK * GXS];    // x-part gates per chunk
    __shared__ __align__(16) float s_h2[52];             // h2 state (pad to 52)

    // ---- one-time preload ----
    #pragma unroll
    for (int i = 0; i < 5; ++i) s_w1[tid + 64 * i] = W1ih[tid + 64 * i];
    if (tid < 52) s_h2[tid] = 0.f;

    // layer-1 per-lane row (lanes 0..19 own gate row tid)
    const int r1 = (tid < NCLS) ? tid : 0;
    float w1h[NH1], bias1;
    #pragma unroll
    for (int j = 0; j < NH1; ++j) w1h[j] = W1hh[r1 * NH1 + j];
    bias1 = b1ih[r1] + b1hh[r1];
    const bool isg = (tid >= 10 && tid < 15);            // g-gate rows -> tanh
    const float isc  = isg ? 2.f : 1.f;
    const float osc  = isg ? 2.f : 1.f;
    const float ooff = isg ? -1.f : 0.f;

    // layer-2 per-lane weights: unit k = tid (lanes 0..49); gate pairs
    // interleaved as float2 to invite v_pk_fma_f32.
    const int k = (tid < NH2) ? tid : 0;
    float2 wAhh[52], wBhh[52];           // A = (i,f) rows, B = (g,o) rows
    #pragma unroll
    for (int j = 0; j < NH2; ++j) {
        wAhh[j] = make_float2(W2hh[(0 * NH2 + k) * NH2 + j],
                              W2hh[(1 * NH2 + k) * NH2 + j]);
        wBhh[j] = make_float2(W2hh[(2 * NH2 + k) * NH2 + j],
                              W2hh[(3 * NH2 + k) * NH2 + j]);
    }
    wAhh[50] = wAhh[51] = wBhh[50] = wBhh[51] = make_float2(0.f, 0.f);
    float2 wAih[NH1], wBih[NH1];
    #pragma unroll
    for (int d = 0; d < NH1; ++d) {
        wAih[d] = make_float2(W2ih[(0 * NH2 + k) * NH1 + d],
                              W2ih[(1 * NH2 + k) * NH1 + d]);
        wBih[d] = make_float2(W2ih[(2 * NH2 + k) * NH1 + d],
                              W2ih[(3 * NH2 + k) * NH1 + d]);
    }
    const float2 biasA = make_float2(b2ih[0 * NH2 + k] + b2hh[0 * NH2 + k],
                                     b2ih[1 * NH2 + k] + b2hh[1 * NH2 + k]);
    const float2 biasB = make_float2(b2ih[2 * NH2 + k] + b2hh[2 * NH2 + k],
                                     b2ih[3 * NH2 + k] + b2hh[3 * NH2 + k]);

    float c1 = 0.f, c2 = 0.f, h2own = 0.f;
    float h1v[NH1];
    #pragma unroll
    for (int j = 0; j < NH1; ++j) h1v[j] = 0.f;

    // x prefetch: lane ll owns step ll of the chunk (16 floats = 4 float4)
    const float* xb = x + (size_t)b * TSEQ * DIN;
    float4 xr[4], xrn[4];
    {
        const float4* xs = (const float4*)(xb + (size_t)tid * DIN);
        #pragma unroll
        for (int i = 0; i < 4; ++i) xr[i] = xs[i];
    }

    __builtin_amdgcn_wave_barrier();

    #pragma unroll 1
    for (int c = 0; c < NCHUNK; ++c) {
        // ---- per-chunk: x-part gates for 64 steps (lane = step) ----
        __builtin_amdgcn_wave_barrier();   // prior chunk's gx reads done (in-order wave)
        const float* xf = (const float*)xr;
        #pragma unroll 4
        for (int g = 0; g < NCLS; ++g) {
            const float4* wr = (const float4*)(s_w1 + g * DIN);
            float4 w0 = wr[0], w1 = wr[1], w2 = wr[2], w3 = wr[3];
            float s = w0.x * xf[0];
            s = fmaf(w0.y, xf[1], s);  s = fmaf(w0.z, xf[2], s);  s = fmaf(w0.w, xf[3], s);
            s = fmaf(w1.x, xf[4], s);  s = fmaf(w1.y, xf[5], s);  s = fmaf(w1.z, xf[6], s);
            s = fmaf(w1.w, xf[7], s);  s = fmaf(w2.x, xf[8], s);  s = fmaf(w2.y, xf[9], s);
            s = fmaf(w2.z, xf[10], s); s = fmaf(w2.w, xf[11], s); s = fmaf(w3.x, xf[12], s);
            s = fmaf(w3.y, xf[13], s); s = fmaf(w3.z, xf[14], s); s = fmaf(w3.w, xf[15], s);
            s_gx[tid * GXS + g] = s;
        }
        // prefetch next chunk's x (latency hidden behind 64 steps)
        {
            const int cn = (c + 1 < NCHUNK) ? c + 1 : c;
            const float4* xs = (const float4*)(xb + ((size_t)cn * CHUNK + tid) * DIN);
            #pragma unroll
            for (int i = 0; i < 4; ++i) xrn[i] = xs[i];
        }
        __builtin_amdgcn_wave_barrier();   // gx writes before step reads (in-order wave)

        float gx_cur = s_gx[r1];           // step 0 x-gate

        #pragma unroll 1
        for (int tt = 0; tt < CHUNK; ++tt) {
            // --- issue long-latency LDS reads first ---
            const int tn = (tt + 1 < CHUNK) ? tt + 1 : tt;
            float gx_next = s_gx[tn * GXS + r1];
            float4 h2r[13];
            {
                const float4* h2v = (const float4*)s_h2;   // h2(t-1), in-order wave
                #pragma unroll
                for (int j = 0; j < 13; ++j) h2r[j] = h2v[j];
            }

            // --- layer 1 (overlaps the read latency) ---
            float g1 = gx_cur + bias1;
            #pragma unroll
            for (int j = 0; j < NH1; ++j) g1 = fmaf(h1v[j], w1h[j], g1);
            float act = fmaf(osc, fast_sigm(isc * g1), ooff);

            float i_ = __shfl(act, tid);
            float f_ = __shfl(act, tid + 5);
            float g_ = __shfl(act, tid + 10);
            float o_ = __shfl(act, tid + 15);
            c1 = fmaf(f_, c1, i_ * g_);
            float h1me = o_ * fast_tanh(c1);
            #pragma unroll
            for (int j = 0; j < NH1; ++j) h1v[j] = __shfl(h1me, j);

            // --- layer 2 ---
            float2 a01 = biasA, a23 = biasB;
            #pragma unroll
            for (int d = 0; d < NH1; ++d) {
                a01 = fma2(h1v[d], wAih[d], a01);
                a23 = fma2(h1v[d], wBih[d], a23);
            }
            #pragma unroll
            for (int j4 = 0; j4 < 13; ++j4) {
                float4 hv = h2r[j4];
                const int j = 4 * j4;
                a01 = fma2(hv.x, wAhh[j + 0], a01);  a23 = fma2(hv.x, wBhh[j + 0], a23);
                a01 = fma2(hv.y, wAhh[j + 1], a01);  a23 = fma2(hv.y, wBhh[j + 1], a23);
                a01 = fma2(hv.z, wAhh[j + 2], a01);  a23 = fma2(hv.z, wBhh[j + 2], a23);
                a01 = fma2(hv.w, wAhh[j + 3], a01);  a23 = fma2(hv.w, wBhh[j + 3], a23);
            }
            float i2 = fast_sigm(a01.x);
            float f2 = fast_sigm(a01.y);
            float g2 = fast_tanh(a23.x);
            float o2 = fast_sigm(a23.y);
            c2 = fmaf(f2, c2, i2 * g2);
            float hnew = o2 * fast_tanh(c2);

            __builtin_amdgcn_wave_barrier();   // keep write after this step's reads
            if (tid < NH2) { s_h2[tid] = hnew; h2own = hnew; }
            __builtin_amdgcn_wave_barrier();

            gx_cur = gx_next;
        }

        #pragma unroll
        for (int i = 0; i < 4; ++i) xr[i] = xrn[i];
    }

    // ---- outputs: result(256,20) @0, last(256,50) @5120 ----
    if (tid < NH2) out[BATCH * NCLS + b * NH2 + tid] = h2own;
    if (tid < NCLS) {
        float acc = bfc[tid];
        const float* wr = Wfc + tid * NH2;
        #pragma unroll
        for (int j = 0; j < NH2; ++j) acc = fmaf(s_h2[j], wr[j], acc);
        out[b * NCLS + tid] = acc;
    }
}

} // namespace

extern "C" void kernel_launch(void* const* d_in, const int* in_sizes, int n_in,
                              void* d_out, int out_size, void* d_ws, size_t ws_size,
                              hipStream_t stream) {
    (void)in_sizes; (void)n_in; (void)d_ws; (void)ws_size; (void)out_size;
    const float* x    = (const float*)d_in[0];
    const float* W1ih = (const float*)d_in[1];
    const float* W1hh = (const float*)d_in[2];
    const float* b1ih = (const float*)d_in[3];
    const float* b1hh = (const float*)d_in[4];
    const float* W2ih = (const float*)d_in[5];
    const float* W2hh = (const float*)d_in[6];
    const float* b2ih = (const float*)d_in[7];
    const float* b2hh = (const float*)d_in[8];
    const float* Wfc  = (const float*)d_in[9];
    const float* bfc  = (const float*)d_in[10];

    lstm_fused_kernel<<<dim3(BATCH), dim3(64), 0, stream>>>(
        x, W1ih, W1hh, b1ih, b1hh, W2ih, W2hh, b2ih, b2hh, Wfc, bfc,
        (float*)d_out);
}

// Round 4
// 1581.343 us; speedup vs baseline: 1.4731x; 1.2758x over previous
//
#include <hip/hip_runtime.h>
#include <math.h>

namespace {

constexpr int TSEQ   = 2048;
constexpr int DIN    = 16;
constexpr int NH1    = 5;
constexpr int NH2    = 50;
constexpr int NCLS   = 20;
constexpr int CHUNK  = 64;
constexpr int NCHUNK = TSEQ / CHUNK;
constexpr int BATCH  = 256;
constexpr int GXS    = 21;   // gx row stride (odd -> conflict-free)

__device__ __forceinline__ float fast_sigm(float x) {
    x = fminf(fmaxf(x, -30.f), 30.f);
    return __fdividef(1.f, 1.f + __expf(-x));
}
// tanh(x) = 2*sigm(2x) - 1
__device__ __forceinline__ float fast_tanh(float x) {
    return fmaf(2.f, fast_sigm(2.f * x), -1.f);
}

// One block = 4 waves = one batch element. Layer-2 split across the CU's
// 4 SIMDs: lane owns (unit,gate) row -> 52 weight VGPRs per lane (register
// resident, no spill). One __syncthreads per step via double-buffered h2.
__global__ __launch_bounds__(256, 1) void lstm_fused_kernel(
    const float* __restrict__ x,     // (256,2048,16)
    const float* __restrict__ W1ih,  // (20,16)
    const float* __restrict__ W1hh,  // (20,5)
    const float* __restrict__ b1ih,  // (20)
    const float* __restrict__ b1hh,  // (20)
    const float* __restrict__ W2ih,  // (200,5)
    const float* __restrict__ W2hh,  // (200,50)
    const float* __restrict__ b2ih,  // (200)
    const float* __restrict__ b2hh,  // (200)
    const float* __restrict__ Wfc,   // (20,50)
    const float* __restrict__ bfc,   // (20)
    float* __restrict__ out)         // result(256,20) ++ last(256,50)
{
    const int b    = blockIdx.x;
    const int tid  = threadIdx.x;
    const int lane = tid & 63;
    const int wv   = tid >> 6;       // wave id 0..3

    __shared__ __align__(16) float s_w1[NCLS * DIN];   // W1ih rows (320 floats)
    __shared__ __align__(16) float s_x[CHUNK * DIN];   // x chunk stage
    __shared__ __align__(16) float s_gx[CHUNK * GXS];  // x-part gates
    __shared__ __align__(16) float s_h2[2][52];        // h2 double buffer

    // ---- one-time preload (320 entries, 256 threads -> strided!) ----
    for (int i = tid; i < NCLS * DIN; i += 256) s_w1[i] = W1ih[i];
    if (tid < 52) { s_h2[0][tid] = 0.f; s_h2[1][tid] = 0.f; }

    // ---- layer-1 per-lane row (replicated on every wave; lanes 0..19) ----
    const int r1 = (lane < NCLS) ? lane : 0;
    float w1h[NH1];
    #pragma unroll
    for (int j = 0; j < NH1; ++j) w1h[j] = W1hh[r1 * NH1 + j];
    const float bias1 = b1ih[r1] + b1hh[r1];
    const bool  isg1  = (lane >= 10 && lane < 15);     // g-gate rows -> tanh
    const float isc1  = isg1 ? 2.f : 1.f;
    const float osc1  = isg1 ? 2.f : 1.f;
    const float off1  = isg1 ? -1.f : 0.f;

    // ---- layer-2 per-lane (unit,gate) row ----
    const int ul   = lane >> 2;                 // local unit 0..15
    const int g    = lane & 3;                  // gate 0..3 (i,f,g,o)
    const int nu   = (wv < 3) ? 13 : 11;        // units per wave (13,13,13,11)
    const bool on2 = (ul < nu);
    const int u    = on2 ? (wv * 13 + ul) : 0;  // global unit 0..49
    const int row  = g * NH2 + u;               // row in (200, ...) weights

    float w2[52];
    {
        const float2* wr = (const float2*)(W2hh + row * NH2);  // 200B rows, 8B aligned
        #pragma unroll
        for (int j = 0; j < 25; ++j) {
            float2 v = wr[j];
            w2[2 * j]     = v.x;
            w2[2 * j + 1] = v.y;
        }
        w2[50] = 0.f; w2[51] = 0.f;
    }
    float w2i[NH1];
    #pragma unroll
    for (int d = 0; d < NH1; ++d) w2i[d] = W2ih[row * NH1 + d];
    const float bias2 = b2ih[row] + b2hh[row];
    const bool  isg2  = (g == 2);
    const float isc2  = isg2 ? 2.f : 1.f;
    const float osc2  = isg2 ? 2.f : 1.f;
    const float off2  = isg2 ? -1.f : 0.f;

    float c1 = 0.f, c2 = 0.f;
    float h1v[NH1];
    #pragma unroll
    for (int j = 0; j < NH1; ++j) h1v[j] = 0.f;

    const float* xb = x + (size_t)b * TSEQ * DIN;
    const float* hcur = s_h2[0];
    float*       hnxt = (float*)s_h2[1];

    __syncthreads();

    #pragma unroll 1
    for (int c = 0; c < NCHUNK; ++c) {
        // ---- stage x chunk (coalesced: 256 x float4 = 1024 floats) ----
        ((float4*)s_x)[tid] = ((const float4*)(xb + (size_t)c * CHUNK * DIN))[tid];
        __syncthreads();

        // ---- x-part gates: thread = (step, q); 5 rows each ----
        {
            const int st = tid >> 2, q = tid & 3;
            const float* xs = s_x + st * DIN;
            float x0 = xs[0],  x1 = xs[1],  x2 = xs[2],  x3 = xs[3];
            float x4 = xs[4],  x5 = xs[5],  x6 = xs[6],  x7 = xs[7];
            float x8 = xs[8],  x9 = xs[9],  xA = xs[10], xB = xs[11];
            float xC = xs[12], xD = xs[13], xE = xs[14], xF = xs[15];
            #pragma unroll
            for (int r = 0; r < 5; ++r) {
                const int rw = q * 5 + r;
                const float* wr = s_w1 + rw * DIN;
                float s = wr[0] * x0;
                s = fmaf(wr[1],  x1, s); s = fmaf(wr[2],  x2, s); s = fmaf(wr[3],  x3, s);
                s = fmaf(wr[4],  x4, s); s = fmaf(wr[5],  x5, s); s = fmaf(wr[6],  x6, s);
                s = fmaf(wr[7],  x7, s); s = fmaf(wr[8],  x8, s); s = fmaf(wr[9],  x9, s);
                s = fmaf(wr[10], xA, s); s = fmaf(wr[11], xB, s); s = fmaf(wr[12], xC, s);
                s = fmaf(wr[13], xD, s); s = fmaf(wr[14], xE, s); s = fmaf(wr[15], xF, s);
                s_gx[st * GXS + rw] = s;
            }
        }
        __syncthreads();

        float gx_cur = s_gx[r1];

        #pragma unroll 2
        for (int tt = 0; tt < CHUNK; ++tt) {
            // --- issue long-latency LDS reads first ---
            const int tn = (tt + 1 < CHUNK) ? tt + 1 : tt;
            float gx_next = s_gx[tn * GXS + r1];
            float4 h2r[13];
            {
                const float4* hv = (const float4*)hcur;   // wave-broadcast reads
                #pragma unroll
                for (int j = 0; j < 13; ++j) h2r[j] = hv[j];
            }

            // --- hh matvec: 4 split accumulators (chain <= 16 deep) ---
            float s0 = bias2, s1 = 0.f, s2 = 0.f, s3 = 0.f;
            #pragma unroll
            for (int j4 = 0; j4 < 3; ++j4) {
                float4 hv = h2r[j4]; const int j = 4 * j4;
                s0 = fmaf(hv.x, w2[j+0], s0); s0 = fmaf(hv.y, w2[j+1], s0);
                s0 = fmaf(hv.z, w2[j+2], s0); s0 = fmaf(hv.w, w2[j+3], s0);
            }
            #pragma unroll
            for (int j4 = 3; j4 < 6; ++j4) {
                float4 hv = h2r[j4]; const int j = 4 * j4;
                s1 = fmaf(hv.x, w2[j+0], s1); s1 = fmaf(hv.y, w2[j+1], s1);
                s1 = fmaf(hv.z, w2[j+2], s1); s1 = fmaf(hv.w, w2[j+3], s1);
            }
            #pragma unroll
            for (int j4 = 6; j4 < 9; ++j4) {
                float4 hv = h2r[j4]; const int j = 4 * j4;
                s2 = fmaf(hv.x, w2[j+0], s2); s2 = fmaf(hv.y, w2[j+1], s2);
                s2 = fmaf(hv.z, w2[j+2], s2); s2 = fmaf(hv.w, w2[j+3], s2);
            }
            #pragma unroll
            for (int j4 = 9; j4 < 13; ++j4) {
                float4 hv = h2r[j4]; const int j = 4 * j4;
                s3 = fmaf(hv.x, w2[j+0], s3); s3 = fmaf(hv.y, w2[j+1], s3);
                s3 = fmaf(hv.z, w2[j+2], s3); s3 = fmaf(hv.w, w2[j+3], s3);
            }

            // --- layer 1 (latency overlaps the hh reads/FMAs) ---
            float g1 = gx_cur + bias1;
            #pragma unroll
            for (int j = 0; j < NH1; ++j) g1 = fmaf(h1v[j], w1h[j], g1);
            float act1 = fmaf(osc1, fast_sigm(isc1 * g1), off1);
            float i1 = __shfl(act1, lane);
            float f1 = __shfl(act1, lane + 5);
            float gg = __shfl(act1, lane + 10);
            float o1 = __shfl(act1, lane + 15);
            c1 = fmaf(f1, c1, i1 * gg);
            float h1me = o1 * fast_tanh(c1);
            #pragma unroll
            for (int j = 0; j < NH1; ++j) h1v[j] = __shfl(h1me, j);

            // --- ih part (depends on fresh h1) ---
            #pragma unroll
            for (int d = 0; d < NH1; ++d) s1 = fmaf(h1v[d], w2i[d], s1);

            float pre = (s0 + s1) + (s2 + s3);
            float a2  = fmaf(osc2, fast_sigm(isc2 * pre), off2);

            // --- quad exchange: i,f,g,o live on 4 adjacent lanes ---
            float v1 = __shfl_xor(a2, 1);
            float v2 = __shfl_xor(a2, 2);
            float v3 = __shfl_xor(a2, 3);
            // on gate-0 lanes: a2=i, v1=f, v2=g, v3=o
            c2 = fmaf(v1, c2, a2 * v2);
            float hn = v3 * fast_tanh(c2);
            if (g == 0 && on2) hnxt[u] = hn;

            __syncthreads();
            { const float* t = hcur; hcur = hnxt; hnxt = (float*)t; }
            gx_cur = gx_next;
        }
    }

    // ---- outputs: result(256,20) @0, last(256,50) @5120 ----
    if (tid < NH2) out[BATCH * NCLS + b * NH2 + tid] = hcur[tid];
    if (tid < NCLS) {
        float acc = bfc[tid];
        const float* wr = Wfc + tid * NH2;
        #pragma unroll
        for (int j = 0; j < NH2; ++j) acc = fmaf(hcur[j], wr[j], acc);
        out[b * NCLS + tid] = acc;
    }
}

} // namespace

extern "C" void kernel_launch(void* const* d_in, const int* in_sizes, int n_in,
                              void* d_out, int out_size, void* d_ws, size_t ws_size,
                              hipStream_t stream) {
    (void)in_sizes; (void)n_in; (void)d_ws; (void)ws_size; (void)out_size;
    const float* x    = (const float*)d_in[0];
    const float* W1ih = (const float*)d_in[1];
    const float* W1hh = (const float*)d_in[2];
    const float* b1ih = (const float*)d_in[3];
    const float* b1hh = (const float*)d_in[4];
    const float* W2ih = (const float*)d_in[5];
    const float* W2hh = (const float*)d_in[6];
    const float* b2ih = (const float*)d_in[7];
    const float* b2hh = (const float*)d_in[8];
    const float* Wfc  = (const float*)d_in[9];
    const float* bfc  = (const float*)d_in[10];

    lstm_fused_kernel<<<dim3(BATCH), dim3(256), 0, stream>>>(
        x, W1ih, W1hh, b1ih, b1hh, W2ih, W2hh, b2ih, b2hh, Wfc, bfc,
        (float*)d_out);
}

// Round 5
// 1014.402 us; speedup vs baseline: 2.2964x; 1.5589x over previous
//
#include <hip/hip_runtime.h>
#include <math.h>

namespace {

constexpr int TSEQ   = 2048;
constexpr int DIN    = 16;
constexpr int NH1    = 5;
constexpr int NH2    = 50;
constexpr int NCLS   = 20;
constexpr int CHUNK  = 64;
constexpr int NCHUNK = TSEQ / CHUNK;
constexpr int BATCH  = 256;
constexpr int GXS    = 21;   // gx row stride (odd -> conflict-free)

typedef float v2f __attribute__((ext_vector_type(2)));

// No clamp: exp(+inf)->inf, rcp(inf)->0 — still correct, and inputs are bounded.
__device__ __forceinline__ float fast_sigm(float x) {
    return __fdividef(1.f, 1.f + __expf(-x));
}
// tanh(x) = 2*sigm(2x) - 1
__device__ __forceinline__ float fast_tanh(float x) {
    return fmaf(2.f, fast_sigm(2.f * x), -1.f);
}

// quad_perm DPP: VALU-speed cross-lane within aligned quads (no DS pipe).
// xor1 = 0xB1 [1,0,3,2], xor2 = 0x4E [2,3,0,1], xor3 = 0x1B [3,2,1,0]
template <int CTRL>
__device__ __forceinline__ float qperm(float v) {
    int i = __builtin_bit_cast(int, v);
    int r = __builtin_amdgcn_update_dpp(i, i, CTRL, 0xf, 0xf, false);
    return __builtin_bit_cast(float, r);
}
__device__ __forceinline__ float rdlane(float v, int lane) {
    return __builtin_bit_cast(float,
        __builtin_amdgcn_readlane(__builtin_bit_cast(int, v), lane));
}

struct L1State {
    float c1;
    float h0, h1, h2, h3, h4;   // wave-uniform (readlane) -> SGPRs
};

// One L1 timestep. Lane 4j+g owns row r=g*5+j (j<5). Gate gather + h1
// broadcast are DPP/readlane — no LDS, no bpermute.
__device__ __forceinline__ void l1_step(float gx, float bias1,
                                        const float* __restrict__ w1h,
                                        float isc1, float osc1, float off1,
                                        L1State& st) {
    float g1 = gx + bias1;
    g1 = fmaf(st.h0, w1h[0], g1);
    g1 = fmaf(st.h1, w1h[1], g1);
    g1 = fmaf(st.h2, w1h[2], g1);
    g1 = fmaf(st.h3, w1h[3], g1);
    g1 = fmaf(st.h4, w1h[4], g1);
    float act = fmaf(osc1, fast_sigm(isc1 * g1), off1);
    float f_ = qperm<0xB1>(act);     // on lane 4j+0: f_j
    float gg = qperm<0x4E>(act);     //               g_j
    float o_ = qperm<0x1B>(act);     //               o_j
    st.c1 = fmaf(f_, st.c1, act * gg);          // valid on lanes 4j+0
    float h1me = o_ * fast_tanh(st.c1);
    st.h0 = rdlane(h1me, 0);
    st.h1 = rdlane(h1me, 4);
    st.h2 = rdlane(h1me, 8);
    st.h3 = rdlane(h1me, 12);
    st.h4 = rdlane(h1me, 16);
}

// One block = 4 waves = one batch element. Layer-2 lane owns (unit,gate) row.
// Cross-lane: DPP quads + readlane SGPR broadcast; LDS only for h2 cross-wave
// publish (1 barrier/step) and the per-chunk gx precompute.
__global__ __launch_bounds__(256, 1) void lstm_fused_kernel(
    const float* __restrict__ x,     // (256,2048,16)
    const float* __restrict__ W1ih,  // (20,16)
    const float* __restrict__ W1hh,  // (20,5)
    const float* __restrict__ b1ih,  // (20)
    const float* __restrict__ b1hh,  // (20)
    const float* __restrict__ W2ih,  // (200,5)
    const float* __restrict__ W2hh,  // (200,50)
    const float* __restrict__ b2ih,  // (200)
    const float* __restrict__ b2hh,  // (200)
    const float* __restrict__ Wfc,   // (20,50)
    const float* __restrict__ bfc,   // (20)
    float* __restrict__ out)         // result(256,20) ++ last(256,50)
{
    const int b    = blockIdx.x;
    const int tid  = threadIdx.x;
    const int lane = tid & 63;
    const int wv   = tid >> 6;       // wave id 0..3

    __shared__ __align__(16) float s_w1[NCLS * DIN];   // W1ih rows (320)
    __shared__ __align__(16) float s_x[CHUNK * DIN];   // x chunk stage
    __shared__ __align__(16) float s_gx[CHUNK * GXS];  // x-part gates
    __shared__ __align__(16) float s_h2[2][52];        // h2 double buffer

    for (int i = tid; i < NCLS * DIN; i += 256) s_w1[i] = W1ih[i];
    if (tid < 52) { s_h2[0][tid] = 0.f; s_h2[1][tid] = 0.f; }

    // ---- layer-1: lane 4j+g owns row r = g*5+j (lanes 0..19) ----
    const int r1 = (lane < NCLS) ? ((lane & 3) * NH1 + (lane >> 2)) : 0;
    float w1h[NH1];
    #pragma unroll
    for (int j = 0; j < NH1; ++j) w1h[j] = W1hh[r1 * NH1 + j];
    const float bias1 = b1ih[r1] + b1hh[r1];
    const bool  isg1  = ((lane & 3) == 2) && (lane < NCLS);  // g gate -> tanh
    const float isc1  = isg1 ? 2.f : 1.f;
    const float osc1  = isg1 ? 2.f : 1.f;
    const float off1  = isg1 ? -1.f : 0.f;

    // ---- layer-2 per-lane (unit,gate) row ----
    const int ul   = lane >> 2;                 // local unit 0..15
    const int g    = lane & 3;                  // gate (i,f,g,o)
    const int nu   = (wv < 3) ? 13 : 11;        // units/wave: 13,13,13,11
    const bool on2 = (ul < nu);
    const int u    = on2 ? (wv * 13 + ul) : 0;  // global unit 0..49
    const int row  = g * NH2 + u;

    v2f w2p[26];                                // hh row as 25 pairs (+pad)
    {
        const float2* wr = (const float2*)(W2hh + row * NH2);
        #pragma unroll
        for (int j = 0; j < 25; ++j) {
            float2 v = wr[j];
            w2p[j] = v2f{v.x, v.y};
        }
        w2p[25] = v2f{0.f, 0.f};
    }
    float w2i[NH1];
    #pragma unroll
    for (int d = 0; d < NH1; ++d) w2i[d] = W2ih[row * NH1 + d];
    const float bias2 = b2ih[row] + b2hh[row];
    const bool  isg2  = (g == 2);
    const float isc2  = isg2 ? 2.f : 1.f;
    const float osc2  = isg2 ? 2.f : 1.f;
    const float off2  = isg2 ? -1.f : 0.f;

    L1State st = {0.f, 0.f, 0.f, 0.f, 0.f, 0.f};
    float c2 = 0.f;

    const float* xb = x + (size_t)b * TSEQ * DIN;
    const float* hcur = s_h2[0];
    float*       hnxt = (float*)s_h2[1];

    __syncthreads();

    #pragma unroll 1
    for (int c = 0; c < NCHUNK; ++c) {
        // ---- stage x chunk (coalesced float4) ----
        ((float4*)s_x)[tid] = ((const float4*)(xb + (size_t)c * CHUNK * DIN))[tid];
        __syncthreads();

        // ---- x-part gates: thread = (step, q); 5 rows each ----
        {
            const int stp = tid >> 2, q = tid & 3;
            const float* xs = s_x + stp * DIN;
            float x0 = xs[0],  x1 = xs[1],  x2 = xs[2],  x3 = xs[3];
            float x4 = xs[4],  x5 = xs[5],  x6 = xs[6],  x7 = xs[7];
            float x8 = xs[8],  x9 = xs[9],  xA = xs[10], xB = xs[11];
            float xC = xs[12], xD = xs[13], xE = xs[14], xF = xs[15];
            #pragma unroll
            for (int r = 0; r < 5; ++r) {
                const int rw = q * 5 + r;
                const float* wr = s_w1 + rw * DIN;
                float s = wr[0] * x0;
                s = fmaf(wr[1],  x1, s); s = fmaf(wr[2],  x2, s); s = fmaf(wr[3],  x3, s);
                s = fmaf(wr[4],  x4, s); s = fmaf(wr[5],  x5, s); s = fmaf(wr[6],  x6, s);
                s = fmaf(wr[7],  x7, s); s = fmaf(wr[8],  x8, s); s = fmaf(wr[9],  x9, s);
                s = fmaf(wr[10], xA, s); s = fmaf(wr[11], xB, s); s = fmaf(wr[12], xC, s);
                s = fmaf(wr[13], xD, s); s = fmaf(wr[14], xE, s); s = fmaf(wr[15], xF, s);
                s_gx[stp * GXS + rw] = s;
            }
        }
        __syncthreads();

        // ---- chunk preamble: L1 for step t0 (all waves, redundant) ----
        l1_step(s_gx[r1], bias1, w1h, isc1, osc1, off1, st);

        #pragma unroll 2
        for (int tt = 0; tt < CHUNK; ++tt) {
            // --- long-latency LDS reads first ---
            const int tn = (tt + 1 < CHUNK) ? tt + 1 : tt;
            float gx_next = s_gx[tn * GXS + r1];
            float4 h2r[13];
            {
                const float4* hv = (const float4*)hcur;   // broadcast reads
                #pragma unroll
                for (int j = 0; j < 13; ++j) h2r[j] = hv[j];
            }

            // --- hh matvec: 26 v_pk_fma_f32 over 4 accumulators ---
            v2f a0 = v2f{bias2, 0.f}, a1 = v2f{0.f, 0.f};
            v2f a2v = v2f{0.f, 0.f},  a3 = v2f{0.f, 0.f};
            #pragma unroll
            for (int j4 = 0; j4 < 13; ++j4) {
                float4 hv = h2r[j4];
                v2f hA = v2f{hv.x, hv.y};
                v2f hB = v2f{hv.z, hv.w};
                const int p = 2 * j4;
                switch (j4 & 3) {
                    case 0:
                        a0 = __builtin_elementwise_fma(hA, w2p[p], a0);
                        a1 = __builtin_elementwise_fma(hB, w2p[p + 1], a1);
                        break;
                    case 1:
                        a2v = __builtin_elementwise_fma(hA, w2p[p], a2v);
                        a3 = __builtin_elementwise_fma(hB, w2p[p + 1], a3);
                        break;
                    case 2:
                        a0 = __builtin_elementwise_fma(hA, w2p[p], a0);
                        a1 = __builtin_elementwise_fma(hB, w2p[p + 1], a1);
                        break;
                    default:
                        a2v = __builtin_elementwise_fma(hA, w2p[p], a2v);
                        a3 = __builtin_elementwise_fma(hB, w2p[p + 1], a3);
                        break;
                }
            }

            // --- ih part with h1(t) from SGPRs ---
            float si = 0.f;
            si = fmaf(st.h0, w2i[0], si);
            si = fmaf(st.h1, w2i[1], si);
            si = fmaf(st.h2, w2i[2], si);
            si = fmaf(st.h3, w2i[3], si);
            si = fmaf(st.h4, w2i[4], si);

            // --- L1 for step t+1 (independent of L2; overlaps it) ---
            if (tt < CHUNK - 1)
                l1_step(gx_next, bias1, w1h, isc1, osc1, off1, st);

            // --- L2 combine ---
            v2f asum = a0 + a1 + a2v + a3;
            float pre = asum.x + asum.y + si;
            float act2 = fmaf(osc2, fast_sigm(isc2 * pre), off2);

            float v1 = qperm<0xB1>(act2);   // on g==0 lanes: f
            float v2 = qperm<0x4E>(act2);   //               g
            float v3 = qperm<0x1B>(act2);   //               o
            c2 = fmaf(v1, c2, act2 * v2);
            float hn = v3 * fast_tanh(c2);
            if (g == 0 && on2) hnxt[u] = hn;

            __syncthreads();
            { const float* t = hcur; hcur = hnxt; hnxt = (float*)t; }
        }
    }

    // ---- outputs: result(256,20) @0, last(256,50) @5120 ----
    if (tid < NH2) out[BATCH * NCLS + b * NH2 + tid] = hcur[tid];
    if (tid < NCLS) {
        float acc = bfc[tid];
        const float* wr = Wfc + tid * NH2;
        #pragma unroll
        for (int j = 0; j < NH2; ++j) acc = fmaf(hcur[j], wr[j], acc);
        out[b * NCLS + tid] = acc;
    }
}

} // namespace

extern "C" void kernel_launch(void* const* d_in, const int* in_sizes, int n_in,
                              void* d_out, int out_size, void* d_ws, size_t ws_size,
                              hipStream_t stream) {
    (void)in_sizes; (void)n_in; (void)d_ws; (void)ws_size; (void)out_size;
    const float* x    = (const float*)d_in[0];
    const float* W1ih = (const float*)d_in[1];
    const float* W1hh = (const float*)d_in[2];
    const float* b1ih = (const float*)d_in[3];
    const float* b1hh = (const float*)d_in[4];
    const float* W2ih = (const float*)d_in[5];
    const float* W2hh = (const float*)d_in[6];
    const float* b2ih = (const float*)d_in[7];
    const float* b2hh = (const float*)d_in[8];
    const float* Wfc  = (const float*)d_in[9];
    const float* bfc  = (const float*)d_in[10];

    lstm_fused_kernel<<<dim3(BATCH), dim3(256), 0, stream>>>(
        x, W1ih, W1hh, b1ih, b1hh, W2ih, W2hh, b2ih, b2hh, Wfc, bfc,
        (float*)d_out);
}